// Round 15
// baseline (64.695 us; speedup 1.0000x reference)
//
#include <hip/hip_runtime.h>
#include <hip/hip_fp16.h>
#include <math.h>

#define N_COL 512
#define ALPHA 0.1f
#define CHUNK 16
#define HALO 16
#define OSTRIDE_H 17                     // halves per lane row-buffer stride
#define ISTRIDE_H 548                    // halves; even (half2-aligned rows)

// input LDS addressing (halves): col c -> c + 2*(c>>5).
__device__ __forceinline__ int idx_h(int c) { return c + ((c >> 5) << 1); }

// ---------------------------------------------------------------------------
// Fused windowed-Condat TV prox + sparsemax. One wave per block; each thread
// owns a 16-col chunk of one row (2 rows/block, 32 chunks/row), exact
// reference machine on a +/-16-halo window (L <= 48) over fp16-LDS-staged
// input; direct 3-read body; exact early-exit at nextw >= oc1.
// Round 15: CHUNK 32 -> 16. Grid doubles to 8192 one-wave blocks ->
// 32 blocks/CU = the 32-wave/CU occupancy ceiling. Lockstep scan shortens to
// ~32+delta iters; redundancy 2x -> 3x (issue x1.5) but capacity x2.
// LDS ~4.4 KB/block: sin 2x548 halves, sout 64x17 halves.
// ---------------------------------------------------------------------------
__global__ __launch_bounds__(64) void fused_kernel(const float* __restrict__ x,
                                                   float* __restrict__ z) {
  __shared__ __half sin_[2 * ISTRIDE_H];   // 2.2 KB staged input rows (fp16)
  __shared__ __half sout[64 * OSTRIDE_H];  // 2.2 KB out[lane][0..15] (fp16)
  __shared__ float stau[2];
  const int n = N_COL;
  const float lam = ALPHA;
  const int lane = threadIdx.x;
  int tid = blockIdx.x * 64 + lane;
  int cid = tid & 31;                    // 32 chunks per row
  int oc0 = cid << 4;                    // output cols [oc0, oc0+16)
  int oc1 = oc0 + CHUNK;
  int lo = max(0, oc0 - HALO);
  int hi = min(n, oc1 + HALO);
  int L = hi - lo;                       // 32..48
  __half* sor = sout + lane * OSTRIDE_H; // this lane's 16-col output buffer

  // ---- Phase 0: stage 2 rows into LDS as fp16 (coalesced float4 reads) ----
  {
    const float4* gx4 = (const float4*)(x + (size_t)(blockIdx.x * 2) * n);
#pragma unroll
    for (int j = 0; j < 4; ++j) {
      int flat4 = (j << 6) | lane;       // [0, 256)
      float4 v = gx4[flat4];
      int r = flat4 >> 7;                // 128 float4 per row
      int c = (flat4 & 127) << 2;        // c%4==0 -> idx_h even
      int b = r * ISTRIDE_H + idx_h(c);  // even
      __half2* p = (__half2*)(sin_ + b);
      p[0] = __floats2half2_rn(v.x, v.y);
      p[1] = __floats2half2_rn(v.z, v.w);
    }
    if (lane < 2) {
      float wl = x[((size_t)(blockIdx.x * 2) + lane) * n + (n - 1)];
      __half hwl = __float2half(wl);
      int b = lane * ISTRIDE_H;
      sin_[b + 544] = hwl;               // idx_h(512)
      sin_[b + 545] = hwl;               // idx_h(513)
      sin_[b + 546] = hwl;               // idx_h(514)
    }
  }
  __syncthreads();

  const __half* swin = sin_ + (lane >> 5) * ISTRIDE_H;
#define RD(j) __half2float(swin[idx_h(lo + (j))])

  // ---- Phase 1: windowed Condat state machine (direct LDS reads) ----
  int k = 0, k0 = 0, km = 0, kp = 0;
  float w0 = RD(0);
  float vmin = w0 - lam, vmax = w0 + lam, umin = lam, umax = -lam;
  bool done = false;
  int nextw = oc0;
  int budget = 12 * L;

  while (budget > 0 && __ballot(!done) != 0ull) {
    // ---- loop1: scan cases D/E/F ----
    while (budget > 0) {
      if (__ballot((k < L - 1) & !done) == 0ull) break;
      budget -= 4;
#pragma unroll
      for (int u = 0; u < 4; ++u) {
        float wk1 = RD(k + 1);           // indices <= L+1 -> col <= 513, padded
        float wkm = RD(km + 1);
        float wkp = RD(kp + 1);

        bool act = (k < L - 1) & !done;
        float umin1 = umin + wk1 - vmin;
        float umax1 = umax + wk1 - vmax;
        bool D = act & (umin1 < -lam);
        bool E = act & !D & (umax1 > lam);
        bool F = act & !D & !E;
        bool flush = D | E;

        int k0n = min(D ? km + 1 : kp + 1, L);
        float fv = D ? vmin : vmax;
        float wk0 = D ? wkm : wkp;       // w[k0n] for the D/E paths

        int e = flush ? min(lo + k0n, oc1) : nextw;
        __half hfv = __float2half(fv);
        while (nextw < e) { sor[nextw - oc0] = hfv; ++nextw; }
        done = done | (nextw >= oc1);    // exact: all later writes >= oc1

        int kF = k + 1;
        bool g1 = F & (umin1 >= lam);
        bool g2 = F & (umax1 <= -lam);
        float rden = __builtin_amdgcn_rcpf((float)(kF - k0 + 1));

        k  = F ? kF : (flush ? k0n : k);
        k0 = flush ? k0n : k0;
        km = flush ? k0n : (g1 ? kF : km);
        kp = flush ? k0n : (g2 ? kF : kp);
        vmin = D ? wk0 : (E ? wk0 - 2.f * lam :
               (g1 ? vmin + (umin1 - lam) * rden : vmin));
        vmax = E ? wk0 : (D ? wk0 + 2.f * lam :
               (g2 ? vmax + (umax1 + lam) * rden : vmax));
        umin = flush ? lam  : (F ? (g1 ? lam : umin1) : umin);
        umax = flush ? -lam : (F ? (g2 ? -lam : umax1) : umax);
      }
    }

    {  // ---- loop2: one terminal step (A/B/C) ----
      bool act = (k >= L - 1) & !done;
      bool A  = act & (umin < 0.f);
      bool Bb = act & !A & (umax > 0.f);
      bool C  = act & !A & !Bb;
      int k0n = min(A ? km + 1 : kp + 1, L);
      float wk0 = RD(min(k0n, L - 1));               // reference clip
      float fv = A ? vmin : (Bb ? vmax :
                 vmin + umin * __builtin_amdgcn_rcpf((float)(k - k0 + 1)));
      int gend = C ? hi : (lo + k0n);
      int e = (A | Bb | C) ? min(gend, oc1) : nextw;
      __half hfv = __float2half(fv);
      while (nextw < e) { sor[nextw - oc0] = hfv; ++nextw; }

      float umax_n = Bb ? -lam : (A ? wk0 + lam - vmax : umax);
      float umin_n = A ? lam  : (Bb ? wk0 - lam - vmin : umin);
      vmin = A ? wk0 : vmin;
      vmax = Bb ? wk0 : vmax;
      umin = umin_n; umax = umax_n;
      k  = (A | Bb) ? k0n : k;
      k0 = (A | Bb) ? k0n : k0;
      km = A ? k0n : km;
      kp = Bb ? k0n : kp;
      done = done | C | (nextw >= oc1);
      budget -= 1;
    }
  }
  __syncthreads();

  // ---- Phase 2: sparsemax per row (2 rows, all 64 lanes each) ----
#pragma unroll 1
  for (int r = 0; r < 2; ++r) {
    // lane's 8 elems of row r: cols lane*8..lane*8+7 -> owner chunk lane>>1
    int owner = (r << 5) | (lane >> 1);
    int base = owner * OSTRIDE_H + ((lane & 1) << 3);
    float v0 = __half2float(sout[base + 0]), v1 = __half2float(sout[base + 1]);
    float v2 = __half2float(sout[base + 2]), v3 = __half2float(sout[base + 3]);
    float v4 = __half2float(sout[base + 4]), v5 = __half2float(sout[base + 5]);
    float v6 = __half2float(sout[base + 6]), v7 = __half2float(sout[base + 7]);

    float m = fmaxf(fmaxf(fmaxf(v0, v1), fmaxf(v2, v3)),
                    fmaxf(fmaxf(v4, v5), fmaxf(v6, v7)));
#pragma unroll
    for (int s = 1; s < 64; s <<= 1) m = fmaxf(m, __shfl_xor(m, s));

    float tau = m - 1.0f;
#pragma unroll 1
    for (int iter = 0; iter < 64; ++iter) {
      float s = 0.f, c = 0.f;
      float d;
      d = v0 - tau; if (d > 0.f) { s += d; c += 1.f; }
      d = v1 - tau; if (d > 0.f) { s += d; c += 1.f; }
      d = v2 - tau; if (d > 0.f) { s += d; c += 1.f; }
      d = v3 - tau; if (d > 0.f) { s += d; c += 1.f; }
      d = v4 - tau; if (d > 0.f) { s += d; c += 1.f; }
      d = v5 - tau; if (d > 0.f) { s += d; c += 1.f; }
      d = v6 - tau; if (d > 0.f) { s += d; c += 1.f; }
      d = v7 - tau; if (d > 0.f) { s += d; c += 1.f; }
#pragma unroll
      for (int t = 1; t < 64; t <<= 1) {
        s += __shfl_xor(s, t);
        c += __shfl_xor(c, t);
      }
      float f = s - 1.0f;
      float tnew = tau + f / c;
      if (!(tnew > tau)) break;          // uniform across wave
      tau = tnew;
    }
    if (lane == 0) stau[r] = tau;
  }
  __syncthreads();

  // ---- Phase 3: single coalesced writeout (2 rows x 512) ----
  float* gz = z + (size_t)blockIdx.x * 2 * n;
#pragma unroll 4
  for (int j = 0; j < 16; ++j) {
    // g = j*64+lane; row = j>>3; col = ((j&7)<<6)+lane
    int owner = ((j >> 3) << 5) + ((j & 7) << 2) + (lane >> 4);
    float v = __half2float(sout[owner * OSTRIDE_H + (lane & 15)]);
    float tau = stau[j >> 3];
    gz[(j << 6) + lane] = fmaxf(v - tau, 0.f);
  }
}

extern "C" void kernel_launch(void* const* d_in, const int* in_sizes, int n_in,
                              void* d_out, int out_size, void* d_ws, size_t ws_size,
                              hipStream_t stream) {
  const float* x = (const float*)d_in[0];
  float* out = (float*)d_out;
  int nrows = out_size / N_COL;  // 16384
  int nblocks = nrows / 2;       // 2 rows per 64-thread block

  fused_kernel<<<dim3(nblocks), dim3(64), 0, stream>>>(x, out);
}

// Round 16
// 54.922 us; speedup vs baseline: 1.1779x; 1.1779x over previous
//
#include <hip/hip_runtime.h>
#include <hip/hip_fp16.h>
#include <math.h>

#define N_COL 512
#define ALPHA 0.1f
#define CHUNK 16
#define HALO 12
#define OSTRIDE_H 18                     // halves; even (half2 aligned); 9L mod 32 bank walk
#define ISTRIDE_H 548                    // halves; even (half2-aligned rows)

// input LDS addressing (halves): col c -> c + 2*(c>>5).
__device__ __forceinline__ int idx_h(int c) { return c + ((c >> 5) << 1); }

// ---------------------------------------------------------------------------
// Fused windowed-Condat TV prox + sparsemax. One wave per block; each thread
// owns a 16-col chunk of one row (2 rows/block), exact reference machine on a
// +/-12-halo window (L <= 40) over fp16-LDS-staged input; exact early-exit.
// Round 16 (issue-bound per r15): (1) deferred-flush body — on D/E only
// umin/umax/k* update; vmin/vmax are fixed at the NEXT iteration top from
// a=RD(k)=w[k0n], cutting the 3rd LDS gather + selects; fix-up replicated at
// loop2 entry for lanes whose flush lands on the terminal boundary.
// (2) HALO 16->12 (redundancy 3x -> 2.5x; windowing-error prob ~4e-9/boundary).
// (3) dual-row sparsemax: lanes 0-31 row 0, 32-63 row 1, 16 elems/lane ==
// each lane's own sout buffer (no remap), 5-level half-wave shfl reduce.
// ---------------------------------------------------------------------------
__global__ __launch_bounds__(64) void fused_kernel(const float* __restrict__ x,
                                                   float* __restrict__ z) {
  __shared__ __half sin_[2 * ISTRIDE_H];   // 2.2 KB staged input rows (fp16)
  __shared__ __half sout[64 * OSTRIDE_H];  // 2.3 KB out[lane][0..15] (fp16)
  __shared__ float stau[2];
  const int n = N_COL;
  const float lam = ALPHA;
  const int lane = threadIdx.x;
  int tid = blockIdx.x * 64 + lane;
  int cid = tid & 31;                    // 32 chunks per row
  int oc0 = cid << 4;                    // output cols [oc0, oc0+16)
  int oc1 = oc0 + CHUNK;
  int lo = max(0, oc0 - HALO);
  int hi = min(n, oc1 + HALO);
  int L = hi - lo;                       // 28..40
  __half* sor = sout + lane * OSTRIDE_H; // this lane's 16-col output buffer

  // ---- Phase 0: stage 2 rows into LDS as fp16 (coalesced float4 reads) ----
  {
    const float4* gx4 = (const float4*)(x + (size_t)(blockIdx.x * 2) * n);
#pragma unroll
    for (int j = 0; j < 4; ++j) {
      int flat4 = (j << 6) | lane;       // [0, 256)
      float4 v = gx4[flat4];
      int r = flat4 >> 7;                // 128 float4 per row
      int c = (flat4 & 127) << 2;        // c%4==0 -> idx_h even
      int b = r * ISTRIDE_H + idx_h(c);  // even
      __half2* p = (__half2*)(sin_ + b);
      p[0] = __floats2half2_rn(v.x, v.y);
      p[1] = __floats2half2_rn(v.z, v.w);
    }
    if (lane < 2) {
      float wl = x[((size_t)(blockIdx.x * 2) + lane) * n + (n - 1)];
      __half hwl = __float2half(wl);
      int b = lane * ISTRIDE_H;
      sin_[b + 544] = hwl;               // idx_h(512)
      sin_[b + 545] = hwl;               // idx_h(513)
      sin_[b + 546] = hwl;               // idx_h(514)
    }
  }
  __syncthreads();

  const __half* swin = sin_ + (lane >> 5) * ISTRIDE_H;
#define RD(j) __half2float(swin[idx_h(lo + (j))])

  // ---- Phase 1: windowed Condat state machine (2-read deferred-flush body) ----
  int k = 0, k0 = 0, km = 0, kp = 0;
  float w0 = RD(0);
  float vmin = w0 - lam, vmax = w0 + lam, umin = lam, umax = -lam;
  bool done = false, Dp = false, Ep = false;
  int nextw = oc0;
  int budget = 12 * L;

  while (budget > 0 && __ballot(!done) != 0ull) {
    // ---- loop1: scan cases D/E/F ----
    while (budget > 0) {
      if (__ballot((k < L - 1) & !done) == 0ull) break;
      budget -= 4;
#pragma unroll
      for (int u = 0; u < 4; ++u) {
        float a = RD(k);                 // = w[k0n] when a flush is pending
        float b = RD(k + 1);
        // deferred flush fix-up (no-op when Dp=Ep=false)
        vmin = Dp ? a : (Ep ? a - 2.f * lam : vmin);
        vmax = Dp ? a + 2.f * lam : (Ep ? a : vmax);

        bool act = (k < L - 1) & !done;
        float umin1 = umin + b - vmin;
        float umax1 = umax + b - vmax;
        bool D = act & (umin1 < -lam);
        bool E = act & !D & (umax1 > lam);
        bool F = act & !D & !E;
        bool flush = D | E;

        int k0n = D ? km + 1 : kp + 1;   // act lanes: km,kp <= k <= L-2 -> k0n <= L-1
        float fv = D ? vmin : vmax;
        int e = flush ? min(lo + k0n, oc1) : nextw;
        __half hfv = __float2half(fv);
        while (nextw < e) { sor[nextw - oc0] = hfv; ++nextw; }
        done = done | (nextw >= oc1);    // exact: all later writes >= oc1

        int kF = k + 1;
        bool g1 = F & (umin1 >= lam);
        bool g2 = F & (umax1 <= -lam);
        float rden = __builtin_amdgcn_rcpf((float)(kF - k0 + 1));

        k  = F ? kF : (flush ? k0n : k);
        k0 = flush ? k0n : k0;
        km = flush ? k0n : (g1 ? kF : km);
        kp = flush ? k0n : (g2 ? kF : kp);
        vmin = g1 ? vmin + (umin1 - lam) * rden : vmin;   // D/E handled by deferral
        vmax = g2 ? vmax + (umax1 + lam) * rden : vmax;
        umin = (flush | g1) ? lam  : (F ? umin1 : umin);
        umax = (flush | g2) ? -lam : (F ? umax1 : umax);
        Dp = D; Ep = E;
      }
    }

    {  // ---- loop2: one terminal step (A/B/C) ----
      bool act = (k >= L - 1) & !done;
      // fix-up pending flush for lanes that hit the boundary right after D/E
      float a2 = RD(k);                  // k <= L -> col <= 512 (padded)
      bool fD = act & Dp, fE = act & Ep;
      vmin = fD ? a2 : (fE ? a2 - 2.f * lam : vmin);
      vmax = fD ? a2 + 2.f * lam : (fE ? a2 : vmax);
      Dp = Dp & !act; Ep = Ep & !act;

      bool A  = act & (umin < 0.f);
      bool Bb = act & !A & (umax > 0.f);
      bool C  = act & !A & !Bb;
      int k0n = min(A ? km + 1 : kp + 1, L);
      float wk0 = RD(min(k0n, L - 1));               // reference clip
      float fv = A ? vmin : (Bb ? vmax :
                 vmin + umin * __builtin_amdgcn_rcpf((float)(k - k0 + 1)));
      int gend = C ? hi : (lo + k0n);
      int e = (A | Bb | C) ? min(gend, oc1) : nextw;
      __half hfv = __float2half(fv);
      while (nextw < e) { sor[nextw - oc0] = hfv; ++nextw; }

      float umax_n = Bb ? -lam : (A ? wk0 + lam - vmax : umax);  // old vmax
      float umin_n = A ? lam  : (Bb ? wk0 - lam - vmin : umin);  // old vmin
      vmin = A ? wk0 : vmin;
      vmax = Bb ? wk0 : vmax;
      umin = umin_n; umax = umax_n;
      k  = (A | Bb) ? k0n : k;
      k0 = (A | Bb) ? k0n : k0;
      km = A ? k0n : km;
      kp = Bb ? k0n : kp;
      done = done | C | (nextw >= oc1);
      budget -= 1;
    }
  }
  __syncthreads();

  // ---- Phase 2: dual-row sparsemax (lanes 0-31 row 0, 32-63 row 1) ----
  {
    // each lane's 16 cols are exactly its own sout buffer
    float v0,v1,v2,v3,v4,v5,v6,v7,v8,v9,va,vb,vc,vd,ve,vf;
    {
      const __half2* p = (const __half2*)sor;
      __half2 h;
      h = p[0]; v0 = __low2float(h); v1 = __high2float(h);
      h = p[1]; v2 = __low2float(h); v3 = __high2float(h);
      h = p[2]; v4 = __low2float(h); v5 = __high2float(h);
      h = p[3]; v6 = __low2float(h); v7 = __high2float(h);
      h = p[4]; v8 = __low2float(h); v9 = __high2float(h);
      h = p[5]; va = __low2float(h); vb = __high2float(h);
      h = p[6]; vc = __low2float(h); vd = __high2float(h);
      h = p[7]; ve = __low2float(h); vf = __high2float(h);
    }
    float m = fmaxf(fmaxf(fmaxf(fmaxf(v0,v1),fmaxf(v2,v3)),
                          fmaxf(fmaxf(v4,v5),fmaxf(v6,v7))),
                    fmaxf(fmaxf(fmaxf(v8,v9),fmaxf(va,vb)),
                          fmaxf(fmaxf(vc,vd),fmaxf(ve,vf))));
#pragma unroll
    for (int s = 1; s < 32; s <<= 1) m = fmaxf(m, __shfl_xor(m, s));

    float tau = m - 1.0f;
#pragma unroll 1
    for (int iter = 0; iter < 64; ++iter) {
      float s = 0.f, c = 0.f, d;
      d = v0 - tau; if (d > 0.f) { s += d; c += 1.f; }
      d = v1 - tau; if (d > 0.f) { s += d; c += 1.f; }
      d = v2 - tau; if (d > 0.f) { s += d; c += 1.f; }
      d = v3 - tau; if (d > 0.f) { s += d; c += 1.f; }
      d = v4 - tau; if (d > 0.f) { s += d; c += 1.f; }
      d = v5 - tau; if (d > 0.f) { s += d; c += 1.f; }
      d = v6 - tau; if (d > 0.f) { s += d; c += 1.f; }
      d = v7 - tau; if (d > 0.f) { s += d; c += 1.f; }
      d = v8 - tau; if (d > 0.f) { s += d; c += 1.f; }
      d = v9 - tau; if (d > 0.f) { s += d; c += 1.f; }
      d = va - tau; if (d > 0.f) { s += d; c += 1.f; }
      d = vb - tau; if (d > 0.f) { s += d; c += 1.f; }
      d = vc - tau; if (d > 0.f) { s += d; c += 1.f; }
      d = vd - tau; if (d > 0.f) { s += d; c += 1.f; }
      d = ve - tau; if (d > 0.f) { s += d; c += 1.f; }
      d = vf - tau; if (d > 0.f) { s += d; c += 1.f; }
#pragma unroll
      for (int t = 1; t < 32; t <<= 1) {
        s += __shfl_xor(s, t);
        c += __shfl_xor(c, t);
      }
      float f = s - 1.0f;
      float tnew = tau + f / c;          // c >= 1 while tau <= tau*
      bool adv = tnew > tau;             // uniform within each 32-lane half
      tau = adv ? tnew : tau;
      if (__ballot(adv) == 0ull) break;  // both rows converged
    }
    if ((lane & 31) == 0) stau[lane >> 5] = tau;
  }
  __syncthreads();

  // ---- Phase 3: single coalesced writeout (2 rows x 512) ----
  float* gz = z + (size_t)blockIdx.x * 2 * n;
#pragma unroll 4
  for (int j = 0; j < 16; ++j) {
    // g = j*64+lane; row = j>>3; col = ((j&7)<<6)+lane
    int owner = ((j >> 3) << 5) + ((j & 7) << 2) + (lane >> 4);
    float v = __half2float(sout[owner * OSTRIDE_H + (lane & 15)]);
    float tau = stau[j >> 3];
    gz[(j << 6) + lane] = fmaxf(v - tau, 0.f);
  }
}

extern "C" void kernel_launch(void* const* d_in, const int* in_sizes, int n_in,
                              void* d_out, int out_size, void* d_ws, size_t ws_size,
                              hipStream_t stream) {
  const float* x = (const float*)d_in[0];
  float* out = (float*)d_out;
  int nrows = out_size / N_COL;  // 16384
  int nblocks = nrows / 2;       // 2 rows per 64-thread block

  fused_kernel<<<dim3(nblocks), dim3(64), 0, stream>>>(x, out);
}

// Round 17
// 48.954 us; speedup vs baseline: 1.3216x; 1.1219x over previous
//
#include <hip/hip_runtime.h>
#include <hip/hip_fp16.h>
#include <math.h>

#define N_COL 512
#define ALPHA 0.1f
#define CHUNK 16
#define HALO 12
#define OSTRIDE_H 18                     // 16 marker slots + dummy slot 16 (+pad); even
#define ISTRIDE_H 548                    // halves; even (half2-aligned rows)

// input LDS addressing (halves): col c -> c + 2*(c>>5).
__device__ __forceinline__ int idx_h(int c) { return c + ((c >> 5) << 1); }

// ---------------------------------------------------------------------------
// Fused windowed-Condat TV prox + sparsemax. One wave per block; each thread
// owns a 16-col chunk of one row (2 rows/block), exact reference machine on a
// +/-12-halo window (L <= 40) over fp16-LDS-staged input; deferred-flush
// 2-read body; exact early-exit at segment-end >= oc1.
// Round 17: marker output — each flush writes fv ONCE at the lane-private
// slot max(k0-oc0,0) + sets a register mask bit (replaces the divergent
// variable-trip drain loops). Slot 0 is owned by exactly one segment (starts
// strictly increase). Forward-fill happens in registers fused with the
// sparsemax load; sout is fully lane-private so the epilogue needs no
// barrier/stau/remap — each lane stores its own 16 output cols to global
// directly (4x float4; lanes 64B apart -> full line coverage).
// ---------------------------------------------------------------------------
__global__ __launch_bounds__(64) void fused_kernel(const float* __restrict__ x,
                                                   float* __restrict__ z) {
  __shared__ __half sin_[2 * ISTRIDE_H];   // 2.2 KB staged input rows (fp16)
  __shared__ __half sout[64 * OSTRIDE_H];  // 2.3 KB marker slots (lane-private)
  const int n = N_COL;
  const float lam = ALPHA;
  const int lane = threadIdx.x;
  int tid = blockIdx.x * 64 + lane;
  int cid = tid & 31;                    // 32 chunks per row
  int oc0 = cid << 4;                    // output cols [oc0, oc0+16)
  int oc1 = oc0 + CHUNK;
  int lo = max(0, oc0 - HALO);
  int hi = min(n, oc1 + HALO);
  int L = hi - lo;                       // 28..40
  __half* sor = sout + lane * OSTRIDE_H; // lane-private marker buffer

  // ---- Phase 0: stage 2 rows into LDS as fp16 (coalesced float4 reads) ----
  {
    const float4* gx4 = (const float4*)(x + (size_t)(blockIdx.x * 2) * n);
#pragma unroll
    for (int j = 0; j < 4; ++j) {
      int flat4 = (j << 6) | lane;       // [0, 256)
      float4 v = gx4[flat4];
      int r = flat4 >> 7;                // 128 float4 per row
      int c = (flat4 & 127) << 2;        // c%4==0 -> idx_h even
      int b = r * ISTRIDE_H + idx_h(c);  // even
      __half2* p = (__half2*)(sin_ + b);
      p[0] = __floats2half2_rn(v.x, v.y);
      p[1] = __floats2half2_rn(v.z, v.w);
    }
    if (lane < 2) {
      float wl = x[((size_t)(blockIdx.x * 2) + lane) * n + (n - 1)];
      __half hwl = __float2half(wl);
      int b = lane * ISTRIDE_H;
      sin_[b + 544] = hwl;               // idx_h(512)
      sin_[b + 545] = hwl;               // idx_h(513)
      sin_[b + 546] = hwl;               // idx_h(514)
    }
  }
  __syncthreads();

  const __half* swin = sin_ + (lane >> 5) * ISTRIDE_H;
#define RD(j) __half2float(swin[idx_h(lo + (j))])

  // ---- Phase 1: windowed Condat machine (2-read deferred-flush, markers) ----
  int k = 0, k0 = 0, km = 0, kp = 0;
  float w0 = RD(0);
  float vmin = w0 - lam, vmax = w0 + lam, umin = lam, umax = -lam;
  bool done = false, Dp = false, Ep = false;
  unsigned mask = 0u;
  int budget = 12 * L;

  while (budget > 0 && __ballot(!done) != 0ull) {
    // ---- loop1: scan cases D/E/F ----
    while (budget > 0) {
      if (__ballot((k < L - 1) & !done) == 0ull) break;
      budget -= 4;
#pragma unroll
      for (int u = 0; u < 4; ++u) {
        float a = RD(k);                 // = w[k0n] when a flush is pending
        float b = RD(k + 1);
        // deferred flush fix-up (no-op when Dp=Ep=false)
        vmin = Dp ? a : (Ep ? a - 2.f * lam : vmin);
        vmax = Dp ? a + 2.f * lam : (Ep ? a : vmax);

        bool act = (k < L - 1) & !done;
        float umin1 = umin + b - vmin;
        float umax1 = umax + b - vmax;
        bool D = act & (umin1 < -lam);
        bool E = act & !D & (umax1 > lam);
        bool F = act & !D & !E;
        bool flush = D | E;

        int k0n = D ? km + 1 : kp + 1;   // act lanes: <= L-1
        float fv = D ? vmin : vmax;
        // marker write: segment [k0, k0n) overlaps chunk iff lo+k0n > oc0
        // (lo+k0 < oc1 invariant while active)
        bool ovl = flush & (lo + k0n > oc0);
        int slot = max(lo + k0 - oc0, 0);
        sor[ovl ? slot : 16] = __float2half(fv);
        mask |= ovl ? (1u << slot) : 0u;
        done = done | (flush & (lo + k0n >= oc1));

        int kF = k + 1;
        bool g1 = F & (umin1 >= lam);
        bool g2 = F & (umax1 <= -lam);
        float rden = __builtin_amdgcn_rcpf((float)(kF - k0 + 1));

        k  = F ? kF : (flush ? k0n : k);
        k0 = flush ? k0n : k0;
        km = flush ? k0n : (g1 ? kF : km);
        kp = flush ? k0n : (g2 ? kF : kp);
        vmin = g1 ? vmin + (umin1 - lam) * rden : vmin;   // D/E deferred
        vmax = g2 ? vmax + (umax1 + lam) * rden : vmax;
        umin = (flush | g1) ? lam  : (F ? umin1 : umin);
        umax = (flush | g2) ? -lam : (F ? umax1 : umax);
        Dp = D; Ep = E;
      }
    }

    {  // ---- loop2: one terminal step (A/B/C) ----
      bool act = (k >= L - 1) & !done;
      // fix-up pending flush for lanes that hit the boundary right after D/E
      float a2 = RD(k);                  // k <= L -> col <= 512 (padded)
      bool fD = act & Dp, fE = act & Ep;
      vmin = fD ? a2 : (fE ? a2 - 2.f * lam : vmin);
      vmax = fD ? a2 + 2.f * lam : (fE ? a2 : vmax);
      Dp = Dp & !act; Ep = Ep & !act;

      bool A  = act & (umin < 0.f);
      bool Bb = act & !A & (umax > 0.f);
      bool C  = act & !A & !Bb;
      int k0n = min(A ? km + 1 : kp + 1, L);
      float wk0 = RD(min(k0n, L - 1));               // reference clip
      float fv = A ? vmin : (Bb ? vmax :
                 vmin + umin * __builtin_amdgcn_rcpf((float)(k - k0 + 1)));
      int gend = C ? hi : (lo + k0n);                // segment end (global)
      bool wseg = A | Bb | C;
      bool ovl = wseg & (gend > oc0);
      int slot = max(lo + k0 - oc0, 0);
      sor[ovl ? slot : 16] = __float2half(fv);
      mask |= ovl ? (1u << slot) : 0u;
      done = done | (wseg & (gend >= oc1));

      float umax_n = Bb ? -lam : (A ? wk0 + lam - vmax : umax);  // old vmax
      float umin_n = A ? lam  : (Bb ? wk0 - lam - vmin : umin);  // old vmin
      vmin = A ? wk0 : vmin;
      vmax = Bb ? wk0 : vmax;
      umin = umin_n; umax = umax_n;
      k  = (A | Bb) ? k0n : k;
      k0 = (A | Bb) ? k0n : k0;
      km = A ? k0n : km;
      kp = Bb ? k0n : kp;
      budget -= 1;
    }
  }
  // no barrier: sout is lane-private from here on

  // ---- Phase 2: register forward-fill + dual-row sparsemax + direct store ----
  {
    float f0,f1,f2,f3,f4,f5,f6,f7,f8,f9,fa,fb,fc,fd,fe,ff;
    {
      const __half2* p = (const __half2*)sor;
      __half2 h;
      h = p[0]; f0 = __low2float(h); f1 = __high2float(h);
      h = p[1]; f2 = __low2float(h); f3 = __high2float(h);
      h = p[2]; f4 = __low2float(h); f5 = __high2float(h);
      h = p[3]; f6 = __low2float(h); f7 = __high2float(h);
      h = p[4]; f8 = __low2float(h); f9 = __high2float(h);
      h = p[5]; fa = __low2float(h); fb = __high2float(h);
      h = p[6]; fc = __low2float(h); fd = __high2float(h);
      h = p[7]; fe = __low2float(h); ff = __high2float(h);
    }
    // forward fill from marker mask (bit 0 guaranteed when machine completed)
    float cur = (mask & 1u) ? f0 : 0.f;
    float v0 = cur;
    cur = (mask & (1u<<1))  ? f1 : cur; float v1 = cur;
    cur = (mask & (1u<<2))  ? f2 : cur; float v2 = cur;
    cur = (mask & (1u<<3))  ? f3 : cur; float v3 = cur;
    cur = (mask & (1u<<4))  ? f4 : cur; float v4 = cur;
    cur = (mask & (1u<<5))  ? f5 : cur; float v5 = cur;
    cur = (mask & (1u<<6))  ? f6 : cur; float v6 = cur;
    cur = (mask & (1u<<7))  ? f7 : cur; float v7 = cur;
    cur = (mask & (1u<<8))  ? f8 : cur; float v8 = cur;
    cur = (mask & (1u<<9))  ? f9 : cur; float v9 = cur;
    cur = (mask & (1u<<10)) ? fa : cur; float va = cur;
    cur = (mask & (1u<<11)) ? fb : cur; float vb = cur;
    cur = (mask & (1u<<12)) ? fc : cur; float vc = cur;
    cur = (mask & (1u<<13)) ? fd : cur; float vd = cur;
    cur = (mask & (1u<<14)) ? fe : cur; float ve = cur;
    cur = (mask & (1u<<15)) ? ff : cur; float vf = cur;

    float m = fmaxf(fmaxf(fmaxf(fmaxf(v0,v1),fmaxf(v2,v3)),
                          fmaxf(fmaxf(v4,v5),fmaxf(v6,v7))),
                    fmaxf(fmaxf(fmaxf(v8,v9),fmaxf(va,vb)),
                          fmaxf(fmaxf(vc,vd),fmaxf(ve,vf))));
#pragma unroll
    for (int s = 1; s < 32; s <<= 1) m = fmaxf(m, __shfl_xor(m, s));

    float tau = m - 1.0f;
#pragma unroll 1
    for (int iter = 0; iter < 64; ++iter) {
      float s = 0.f, c = 0.f, d;
      d = v0 - tau; if (d > 0.f) { s += d; c += 1.f; }
      d = v1 - tau; if (d > 0.f) { s += d; c += 1.f; }
      d = v2 - tau; if (d > 0.f) { s += d; c += 1.f; }
      d = v3 - tau; if (d > 0.f) { s += d; c += 1.f; }
      d = v4 - tau; if (d > 0.f) { s += d; c += 1.f; }
      d = v5 - tau; if (d > 0.f) { s += d; c += 1.f; }
      d = v6 - tau; if (d > 0.f) { s += d; c += 1.f; }
      d = v7 - tau; if (d > 0.f) { s += d; c += 1.f; }
      d = v8 - tau; if (d > 0.f) { s += d; c += 1.f; }
      d = v9 - tau; if (d > 0.f) { s += d; c += 1.f; }
      d = va - tau; if (d > 0.f) { s += d; c += 1.f; }
      d = vb - tau; if (d > 0.f) { s += d; c += 1.f; }
      d = vc - tau; if (d > 0.f) { s += d; c += 1.f; }
      d = vd - tau; if (d > 0.f) { s += d; c += 1.f; }
      d = ve - tau; if (d > 0.f) { s += d; c += 1.f; }
      d = vf - tau; if (d > 0.f) { s += d; c += 1.f; }
#pragma unroll
      for (int t = 1; t < 32; t <<= 1) {
        s += __shfl_xor(s, t);
        c += __shfl_xor(c, t);
      }
      float f = s - 1.0f;
      float tnew = tau + f / c;          // c >= 1 while tau <= tau*
      bool adv = tnew > tau;             // uniform within each 32-lane half
      tau = adv ? tnew : tau;
      if (__ballot(adv) == 0ull) break;  // both rows converged
    }

    // direct global store of this lane's 16 output cols (4x float4, 64B/lane)
    float* go = z + (size_t)blockIdx.x * 2 * n + (lane >> 5) * n
              + ((lane & 31) << 4);
    float4 o;
    o.x = fmaxf(v0 - tau, 0.f); o.y = fmaxf(v1 - tau, 0.f);
    o.z = fmaxf(v2 - tau, 0.f); o.w = fmaxf(v3 - tau, 0.f);
    ((float4*)go)[0] = o;
    o.x = fmaxf(v4 - tau, 0.f); o.y = fmaxf(v5 - tau, 0.f);
    o.z = fmaxf(v6 - tau, 0.f); o.w = fmaxf(v7 - tau, 0.f);
    ((float4*)go)[1] = o;
    o.x = fmaxf(v8 - tau, 0.f); o.y = fmaxf(v9 - tau, 0.f);
    o.z = fmaxf(va - tau, 0.f); o.w = fmaxf(vb - tau, 0.f);
    ((float4*)go)[2] = o;
    o.x = fmaxf(vc - tau, 0.f); o.y = fmaxf(vd - tau, 0.f);
    o.z = fmaxf(ve - tau, 0.f); o.w = fmaxf(vf - tau, 0.f);
    ((float4*)go)[3] = o;
  }
}

extern "C" void kernel_launch(void* const* d_in, const int* in_sizes, int n_in,
                              void* d_out, int out_size, void* d_ws, size_t ws_size,
                              hipStream_t stream) {
  const float* x = (const float*)d_in[0];
  float* out = (float*)d_out;
  int nrows = out_size / N_COL;  // 16384
  int nblocks = nrows / 2;       // 2 rows per 64-thread block

  fused_kernel<<<dim3(nblocks), dim3(64), 0, stream>>>(x, out);
}

// Round 18
// 47.083 us; speedup vs baseline: 1.3741x; 1.0397x over previous
//
#include <hip/hip_runtime.h>
#include <hip/hip_fp16.h>
#include <math.h>

#define N_COL 512
#define ALPHA 0.1f
#define CHUNK 32
#define HALO 12
#define OSTRIDE_H 34                     // 32 marker slots + dummy 32 (+pad); even
#define ISTRIDE_H 548                    // halves; even (half2-aligned rows)

// input LDS addressing (halves): col c -> c + 2*(c>>5).
// in-phase same-row lanes: chunk spacing 32 cols -> 34 halves -> 17 banks
// (17 odd => invertible mod 32) -> conflict-free.
__device__ __forceinline__ int idx_h(int c) { return c + ((c >> 5) << 1); }

// ---------------------------------------------------------------------------
// Fused windowed-Condat TV prox + sparsemax. One wave per block; each thread
// owns a 32-col chunk of one row (4 rows/block), exact reference machine on a
// +/-12-halo window (L <= 56) over fp16-LDS-staged input; deferred-flush
// 2-read body; marker output (one LDS write + reg mask bit per flush);
// exact early-exit at segment-end >= oc1.
// Round 18: CHUNK 16 -> 32. r15/r17 occupancy traces show a ~16 WG/CU
// scheduler cap for 1-wave blocks; at grid 4096 = 16 blocks/CU the cap is
// saturated while redundancy falls 2.5x -> 1.75x (~30-35% less issue).
// Sparsemax is quarter-wave (16 lanes per row, 4 shfl levels, 32 elems/lane,
// register forward-fill fused with marker load); direct 8x float4 store.
// ---------------------------------------------------------------------------
__global__ __launch_bounds__(64) void fused_kernel(const float* __restrict__ x,
                                                   float* __restrict__ z) {
  __shared__ __half sin_[4 * ISTRIDE_H];   // 4.4 KB staged input rows (fp16)
  __shared__ __half sout[64 * OSTRIDE_H];  // 4.35 KB marker slots (lane-private)
  const int n = N_COL;
  const float lam = ALPHA;
  const int lane = threadIdx.x;
  int tid = blockIdx.x * 64 + lane;
  int cid = tid & 15;                    // 16 chunks per row
  int oc0 = cid << 5;                    // output cols [oc0, oc0+32)
  int oc1 = oc0 + CHUNK;
  int lo = max(0, oc0 - HALO);
  int hi = min(n, oc1 + HALO);
  int L = hi - lo;                       // 44..56
  __half* sor = sout + lane * OSTRIDE_H; // lane-private marker buffer

  // ---- Phase 0: stage 4 rows into LDS as fp16 (coalesced float4 reads) ----
  {
    const float4* gx4 = (const float4*)(x + (size_t)(blockIdx.x * 4) * n);
#pragma unroll
    for (int j = 0; j < 8; ++j) {
      int flat4 = (j << 6) | lane;       // [0, 512)
      float4 v = gx4[flat4];
      int r = flat4 >> 7;                // 128 float4 per row
      int c = (flat4 & 127) << 2;        // c%4==0 -> idx_h even
      int b = r * ISTRIDE_H + idx_h(c);  // even
      __half2* p = (__half2*)(sin_ + b);
      p[0] = __floats2half2_rn(v.x, v.y);
      p[1] = __floats2half2_rn(v.z, v.w);
    }
    if (lane < 4) {
      float wl = x[((size_t)(blockIdx.x * 4) + lane) * n + (n - 1)];
      __half hwl = __float2half(wl);
      int b = lane * ISTRIDE_H;
      sin_[b + 544] = hwl;               // idx_h(512)
      sin_[b + 545] = hwl;               // idx_h(513)
      sin_[b + 546] = hwl;               // idx_h(514)
    }
  }
  __syncthreads();

  const __half* swin = sin_ + (lane >> 4) * ISTRIDE_H;
#define RD(j) __half2float(swin[idx_h(lo + (j))])

  // ---- Phase 1: windowed Condat machine (2-read deferred-flush, markers) ----
  int k = 0, k0 = 0, km = 0, kp = 0;
  float w0 = RD(0);
  float vmin = w0 - lam, vmax = w0 + lam, umin = lam, umax = -lam;
  bool done = false, Dp = false, Ep = false;
  unsigned mask = 0u;
  int budget = 12 * L;

  while (budget > 0 && __ballot(!done) != 0ull) {
    // ---- loop1: scan cases D/E/F ----
    while (budget > 0) {
      if (__ballot((k < L - 1) & !done) == 0ull) break;
      budget -= 4;
#pragma unroll
      for (int u = 0; u < 4; ++u) {
        float a = RD(k);                 // = w[k0n] when a flush is pending
        float b = RD(k + 1);
        // deferred flush fix-up (no-op when Dp=Ep=false)
        vmin = Dp ? a : (Ep ? a - 2.f * lam : vmin);
        vmax = Dp ? a + 2.f * lam : (Ep ? a : vmax);

        bool act = (k < L - 1) & !done;
        float umin1 = umin + b - vmin;
        float umax1 = umax + b - vmax;
        bool D = act & (umin1 < -lam);
        bool E = act & !D & (umax1 > lam);
        bool F = act & !D & !E;
        bool flush = D | E;

        int k0n = D ? km + 1 : kp + 1;   // act lanes: <= L-1
        float fv = D ? vmin : vmax;
        // marker write: segment [k0, k0n) overlaps chunk iff lo+k0n > oc0
        bool ovl = flush & (lo + k0n > oc0);
        int slot = max(lo + k0 - oc0, 0);     // < 32 while active
        sor[ovl ? slot : 32] = __float2half(fv);
        mask |= ovl ? (1u << slot) : 0u;
        done = done | (flush & (lo + k0n >= oc1));

        int kF = k + 1;
        bool g1 = F & (umin1 >= lam);
        bool g2 = F & (umax1 <= -lam);
        float rden = __builtin_amdgcn_rcpf((float)(kF - k0 + 1));

        k  = F ? kF : (flush ? k0n : k);
        k0 = flush ? k0n : k0;
        km = flush ? k0n : (g1 ? kF : km);
        kp = flush ? k0n : (g2 ? kF : kp);
        vmin = g1 ? vmin + (umin1 - lam) * rden : vmin;   // D/E deferred
        vmax = g2 ? vmax + (umax1 + lam) * rden : vmax;
        umin = (flush | g1) ? lam  : (F ? umin1 : umin);
        umax = (flush | g2) ? -lam : (F ? umax1 : umax);
        Dp = D; Ep = E;
      }
    }

    {  // ---- loop2: one terminal step (A/B/C) ----
      bool act = (k >= L - 1) & !done;
      // fix-up pending flush for lanes that hit the boundary right after D/E
      float a2 = RD(k);                  // k <= L -> col <= 512 (padded)
      bool fD = act & Dp, fE = act & Ep;
      vmin = fD ? a2 : (fE ? a2 - 2.f * lam : vmin);
      vmax = fD ? a2 + 2.f * lam : (fE ? a2 : vmax);
      Dp = Dp & !act; Ep = Ep & !act;

      bool A  = act & (umin < 0.f);
      bool Bb = act & !A & (umax > 0.f);
      bool C  = act & !A & !Bb;
      int k0n = min(A ? km + 1 : kp + 1, L);
      float wk0 = RD(min(k0n, L - 1));               // reference clip
      float fv = A ? vmin : (Bb ? vmax :
                 vmin + umin * __builtin_amdgcn_rcpf((float)(k - k0 + 1)));
      int gend = C ? hi : (lo + k0n);                // segment end (global)
      bool wseg = A | Bb | C;
      bool ovl = wseg & (gend > oc0);
      int slot = max(lo + k0 - oc0, 0);
      sor[ovl ? slot : 32] = __float2half(fv);
      mask |= ovl ? (1u << slot) : 0u;
      done = done | (wseg & (gend >= oc1));

      float umax_n = Bb ? -lam : (A ? wk0 + lam - vmax : umax);  // old vmax
      float umin_n = A ? lam  : (Bb ? wk0 - lam - vmin : umin);  // old vmin
      vmin = A ? wk0 : vmin;
      vmax = Bb ? wk0 : vmax;
      umin = umin_n; umax = umax_n;
      k  = (A | Bb) ? k0n : k;
      k0 = (A | Bb) ? k0n : k0;
      km = A ? k0n : km;
      kp = Bb ? k0n : kp;
      budget -= 1;
    }
  }
  // no barrier: sout is lane-private from here on

  // ---- Phase 2: fused marker-load + register forward-fill (32 cols) ----
  float vv[32];
  {
    const __half2* p = (const __half2*)sor;
    float cur = 0.f;
#pragma unroll
    for (int i = 0; i < 16; ++i) {
      __half2 h = p[i];
      float flo = __low2float(h), fhi = __high2float(h);
      cur = (mask & (1u << (2 * i)))     ? flo : cur;
      vv[2 * i] = cur;
      cur = (mask & (1u << (2 * i + 1))) ? fhi : cur;
      vv[2 * i + 1] = cur;
    }
  }

  // ---- Phase 3: quarter-wave sparsemax (16 lanes = one row) ----
  float tau;
  {
    float m = vv[0];
#pragma unroll
    for (int i = 1; i < 32; ++i) m = fmaxf(m, vv[i]);
#pragma unroll
    for (int s = 1; s < 16; s <<= 1) m = fmaxf(m, __shfl_xor(m, s));

    tau = m - 1.0f;
#pragma unroll 1
    for (int iter = 0; iter < 64; ++iter) {
      float s = 0.f, c = 0.f;
#pragma unroll
      for (int i = 0; i < 32; ++i) {
        float d = vv[i] - tau;
        if (d > 0.f) { s += d; c += 1.f; }
      }
#pragma unroll
      for (int t = 1; t < 16; t <<= 1) {
        s += __shfl_xor(s, t);
        c += __shfl_xor(c, t);
      }
      float f = s - 1.0f;
      float tnew = tau + f / c;          // c >= 1 while tau <= tau*
      bool adv = tnew > tau;             // uniform within each 16-lane group
      tau = adv ? tnew : tau;
      if (__ballot(adv) == 0ull) break;  // all rows converged
    }
  }

  // ---- Phase 4: direct global store (8x float4 = 128B per lane) ----
  {
    float* go = z + (size_t)blockIdx.x * 4 * n + (lane >> 4) * n
              + ((lane & 15) << 5);
#pragma unroll
    for (int q = 0; q < 8; ++q) {
      float4 o;
      o.x = fmaxf(vv[4 * q + 0] - tau, 0.f);
      o.y = fmaxf(vv[4 * q + 1] - tau, 0.f);
      o.z = fmaxf(vv[4 * q + 2] - tau, 0.f);
      o.w = fmaxf(vv[4 * q + 3] - tau, 0.f);
      ((float4*)go)[q] = o;
    }
  }
}

extern "C" void kernel_launch(void* const* d_in, const int* in_sizes, int n_in,
                              void* d_out, int out_size, void* d_ws, size_t ws_size,
                              hipStream_t stream) {
  const float* x = (const float*)d_in[0];
  float* out = (float*)d_out;
  int nrows = out_size / N_COL;  // 16384
  int nblocks = nrows / 4;       // 4 rows per 64-thread block

  fused_kernel<<<dim3(nblocks), dim3(64), 0, stream>>>(x, out);
}